// Round 6
// baseline (488.151 us; speedup 1.0000x reference)
//
#include <hip/hip_runtime.h>
#include <hip/hip_bf16.h>

typedef __bf16 bf16x8 __attribute__((ext_vector_type(8)));
typedef float  f32x4  __attribute__((ext_vector_type(4)));
typedef unsigned int u32;

// async global->LDS, 16B/lane; LDS dest = wave-uniform base + lane*16 (m97/m104)
#define GLD_LDS16(gp, lp) __builtin_amdgcn_global_load_lds( \
    (const __attribute__((address_space(1))) u32*)(gp), \
    (__attribute__((address_space(3))) u32*)(lp), 16, 0, 0)

// DPP cyclic rotate within 16-lane rows (row_ror:N = 0x120|N) — VALU-pipe cross-lane
template<int CTRL>
__device__ __forceinline__ float dpp_rot(float x) {
    int y = __builtin_amdgcn_update_dpp(__float_as_int(x), __float_as_int(x),
                                        CTRL, 0xF, 0xF, false);
    return __int_as_float(y);
}
__device__ __forceinline__ float rowmax16(float x) {
    x = fmaxf(x, dpp_rot<0x121>(x));
    x = fmaxf(x, dpp_rot<0x122>(x));
    x = fmaxf(x, dpp_rot<0x124>(x));
    x = fmaxf(x, dpp_rot<0x128>(x));
    return x;
}
__device__ __forceinline__ float rowsum16(float x) {
    x += dpp_rot<0x121>(x);
    x += dpp_rot<0x122>(x);
    x += dpp_rot<0x124>(x);
    x += dpp_rot<0x128>(x);
    return x;
}

// ---------------------------------------------------------------- converts

__global__ __launch_bounds__(256) void f32_to_bf16_kernel(
    const float* __restrict__ in, __bf16* __restrict__ out, size_t n) {
    size_t i = ((size_t)blockIdx.x * 256 + threadIdx.x) * 8;
    if (i >= n) return;
    float4 a = *(const float4*)(in + i);
    float4 b = *(const float4*)(in + i + 4);
    bf16x8 v;
    v[0] = (__bf16)a.x; v[1] = (__bf16)a.y; v[2] = (__bf16)a.z; v[3] = (__bf16)a.w;
    v[4] = (__bf16)b.x; v[5] = (__bf16)b.y; v[6] = (__bf16)b.z; v[7] = (__bf16)b.w;
    *(bf16x8*)(out + i) = v;
}

// W[K][N] fp32  ->  Wt[N][K] bf16   (32x32 LDS tile transpose)
__global__ __launch_bounds__(256) void transpose_to_bf16_kernel(
    const float* __restrict__ W, __bf16* __restrict__ Wt, int K, int N) {
    __shared__ float tile[32][33];
    int n0 = blockIdx.x * 32, k0 = blockIdx.y * 32;
    int tx = threadIdx.x, ty = threadIdx.y;  // 32 x 8
    #pragma unroll
    for (int i = 0; i < 32; i += 8)
        tile[ty + i][tx] = W[(size_t)(k0 + ty + i) * N + n0 + tx];
    __syncthreads();
    #pragma unroll
    for (int i = 0; i < 32; i += 8)
        Wt[(size_t)(n0 + ty + i) * K + k0 + tx] = (__bf16)tile[tx][ty + i];
}

// bqkv = concat(bq[2048], bkv[1024])
__global__ __launch_bounds__(256) void concat_bias_kernel(
    const float* __restrict__ bq, const float* __restrict__ bkv,
    float* __restrict__ bqkv) {
    int i = blockIdx.x * 256 + threadIdx.x;
    if (i < 2048) bqkv[i] = bq[i];
    else if (i < 3072) bqkv[i] = bkv[i - 2048];
}

// V cols of qkv [b*S+s][3072] (cols 2560..3071) -> Vt[(b*4+kvh)*128 + d][S]
__global__ __launch_bounds__(256) void transpose_v_kernel(
    const __bf16* __restrict__ qkv, __bf16* __restrict__ vtg, int S) {
    __shared__ __bf16 tile[32][33];
    int s0 = blockIdx.x * 32, d0 = blockIdx.y * 32, z = blockIdx.z;  // z = b*4+kvh
    int b = z >> 2, kvh = z & 3;
    int tx = threadIdx.x, ty = threadIdx.y;  // 32 x 8
    #pragma unroll
    for (int i = 0; i < 32; i += 8)
        tile[ty + i][tx] =
            qkv[((size_t)b * S + s0 + ty + i) * 3072 + 2560 + kvh * 128 + d0 + tx];
    __syncthreads();
    #pragma unroll
    for (int i = 0; i < 32; i += 8)
        vtg[((size_t)z * 128 + d0 + ty + i) * S + s0 + tx] = tile[tx][ty + i];
}

// ---------------------------------------------------------------- GEMM (m97: BK=64)
// C[M][N] = A[M][K](bf16) @ Bt[N][K](bf16)^T + bias[N], fp32 accumulate.
#define BM 128
#define BN 128
#define BK 64

template <typename OutT>
__global__ __launch_bounds__(256) void gemm_bt_bias_kernel(
    const __bf16* __restrict__ A, const __bf16* __restrict__ Bt,
    const float* __restrict__ bias, OutT* __restrict__ C,
    int M, int N, int K) {
    __shared__ __bf16 As[BM * BK];  // 16 KB, 128B rows, unpadded (DMA dest)
    __shared__ __bf16 Bs[BN * BK];
    int tid  = threadIdx.x;
    int bm   = blockIdx.x;
    int bn   = blockIdx.y;
    int wave = tid >> 6;
    int lane = tid & 63;
    int wm   = (wave >> 1) * 64;
    int wn   = (wave & 1) * 64;
    int quad = lane >> 4;
    int l16  = lane & 15;
    int gr   = wave * 32 + (lane >> 3);   // staging row (+i*8)
    int gc   = (lane & 7) * 8;            // staging col (bf16 elems)

    f32x4 acc[4][4];
    f32x4 zero = {0.f, 0.f, 0.f, 0.f};
    #pragma unroll
    for (int i = 0; i < 4; ++i)
        #pragma unroll
        for (int j = 0; j < 4; ++j) acc[i][j] = zero;

    const __bf16* Abase = A  + (size_t)(bm * BM) * K;
    const __bf16* Bbase = Bt + (size_t)(bn * BN) * K;

    for (int k0 = 0; k0 < K; k0 += BK) {
        if (k0) __syncthreads();
        #pragma unroll
        for (int i = 0; i < 4; ++i) {
            GLD_LDS16(Abase + (size_t)(gr + i * 8) * K + k0 + gc,
                      &As[(wave * 32 + i * 8) * BK]);
            GLD_LDS16(Bbase + (size_t)(gr + i * 8) * K + k0 + gc,
                      &Bs[(wave * 32 + i * 8) * BK]);
        }
        __syncthreads();  // drains vmcnt -> LDS data visible

        bf16x8 af[4][2], bf[4][2];
        #pragma unroll
        for (int i = 0; i < 4; ++i)
            #pragma unroll
            for (int kc = 0; kc < 2; ++kc)
                af[i][kc] = *(bf16x8*)&As[(wm + i * 16 + l16) * BK + kc * 32 + quad * 8];
        #pragma unroll
        for (int j = 0; j < 4; ++j)
            #pragma unroll
            for (int kc = 0; kc < 2; ++kc)
                bf[j][kc] = *(bf16x8*)&Bs[(wn + j * 16 + l16) * BK + kc * 32 + quad * 8];
        #pragma unroll
        for (int kc = 0; kc < 2; ++kc)
            #pragma unroll
            for (int i = 0; i < 4; ++i)
                #pragma unroll
                for (int j = 0; j < 4; ++j)
                    acc[i][j] = __builtin_amdgcn_mfma_f32_16x16x32_bf16(
                        af[i][kc], bf[j][kc], acc[i][j], 0, 0, 0);
    }

    // D layout (HW-verified m89/m91): row = quad*4+reg, col = l16
    #pragma unroll
    for (int i = 0; i < 4; ++i) {
        int row = bm * BM + wm + i * 16 + quad * 4;
        #pragma unroll
        for (int j = 0; j < 4; ++j) {
            int col  = bn * BN + wn + j * 16 + l16;
            float bv = bias[col];
            #pragma unroll
            for (int r = 0; r < 4; ++r)
                C[(size_t)(row + r) * N + col] = (OutT)(acc[i][j][r] + bv);
        }
    }
}

// ---------------------------------------------------------------- RoPE (in-place, bf16)
// slots 0..15 = q heads (coloff 0), slots 16..19 = k heads (coloff 2048)
__global__ __launch_bounds__(256) void rope_kernel(
    __bf16* __restrict__ buf, const float* __restrict__ cosp,
    const float* __restrict__ sinp, int S, int total) {
    int idx = blockIdx.x * 256 + threadIdx.x;
    if (idx >= total) return;
    int d    = idx & 63;
    int t2   = idx >> 6;
    int slot = t2 % 20;
    int r    = t2 / 20;
    int s    = r & (S - 1);
    int coloff = (slot < 16) ? slot * 128 : 2048 + (slot - 16) * 128;
    size_t base = (size_t)r * 3072 + coloff;
    float x1 = (float)buf[base + d];
    float x2 = (float)buf[base + d + 64];
    float c  = cosp[s * 64 + d];
    float sn = sinp[s * 64 + d];
    buf[base + d]      = (__bf16)(x1 * c - x2 * sn);
    buf[base + d + 64] = (__bf16)(x1 * sn + x2 * c);
}

// ---------------------------------------------------------------- MFMA flash attention
// 8 waves/block (512 thr), Q-tile 128 rows (16/wave), K-tile 64 keys.
// K: double-buffered LDS via global_load_lds, shared by all 8 waves.
// V: register prefetch from dim-major vtg (issued before QK, used after softmax).
// Softmax cross-lane via DPP; l-sum deferred to epilogue.
// C/D layout (m89/m91): row = quad*4+reg, col = l16.
#define PS_STR 68   // 64 keys + 4 pad: P-store banks = 8*quad + l16/2 -> conflict-free

__global__ __launch_bounds__(512, 4) void flash_mfma_kernel(
    const __bf16* __restrict__ qkv,  // [B*S][3072]: q|k(2048..2559)|v
    const __bf16* __restrict__ vtg,  // [(b*4+kvh)*128 + d][S]  (V transposed)
    __bf16* __restrict__ vo,         // [B*S][2048]
    const int* __restrict__ causal_p, int S) {
    __shared__ __bf16 Ks[2][64 * 128];       // 2 x 16 KB, chunk-swizzled
    __shared__ __bf16 Ps[8 * 16 * PS_STR];   // 17 KB, per-wave P transform

    const int QKV = 3072;
    int tid  = threadIdx.x;
    int wave = tid >> 6;         // 0..7
    int lane = tid & 63;
    int quad = lane >> 4;
    int l16  = lane & 15;
    int id   = blockIdx.x;
    int xcd  = id & 7;           // id%8 -> (b,kvh): XCD L2 affinity
    int b    = xcd >> 2;
    int kvh  = xcd & 3;
    int rest = id >> 3;          // 0..63
    int hh   = rest & 3;
    int qt   = 15 - (rest >> 2); // heavy (high-qt) blocks dispatch first
    int h    = kvh * 4 + hh;
    int q0   = qt * 128;
    int causal = causal_p[0];
    const float SCALE = 0.08838834764831845f;  // 1/sqrt(128)

    const __bf16* vB = vtg + ((size_t)(b * 4 + kvh) * 128) * S;
    int nt = causal ? (2 * qt + 2) : (S / 64);

    // Q A-frags: lane holds row l16 of the wave's 16-row tile
    bf16x8 a_frag[4];
    {
        size_t qrow = ((size_t)b * S + q0 + wave * 16 + l16) * QKV + h * 128 + quad * 8;
        #pragma unroll
        for (int kc = 0; kc < 4; ++kc)
            a_frag[kc] = *(const bf16x8*)(qkv + qrow + kc * 32);
    }

    f32x4 o_acc[8];
    f32x4 zero4 = {0.f, 0.f, 0.f, 0.f};
    #pragma unroll
    for (int dt = 0; dt < 8; ++dt) o_acc[dt] = zero4;
    float m_[4], l_[4];  // m_: row max; l_: PER-LANE partial sum
    #pragma unroll
    for (int r = 0; r < 4; ++r) { m_[r] = -1e30f; l_[r] = 0.f; }
    int qrow_d = q0 + wave * 16 + quad * 4;

    // prologue: DMA K(0) -> Ks[0]; wave w stages chunks 2w, 2w+1
    #pragma unroll
    for (int i = 0; i < 2; ++i) {
        int c = wave * 2 + i;                 // c = jt*4 + kc
        size_t kg = ((size_t)b * S + (c >> 2) * 16 + l16) * QKV
                    + 2048 + kvh * 128 + (c & 3) * 32 + quad * 8;
        GLD_LDS16(qkv + kg, &Ks[0][c * 512]);
    }

    for (int t = 0; t < nt; ++t) {
        int cur = t & 1;
        __syncthreads();  // drains vmcnt: K(t) DMA complete; syncs all 8 waves
        if (t + 1 < nt) {  // prefetch K(t+1) into the other buffer
            #pragma unroll
            for (int i = 0; i < 2; ++i) {
                int c = wave * 2 + i;
                size_t kg = ((size_t)b * S + (t + 1) * 64 + (c >> 2) * 16 + l16) * QKV
                            + 2048 + kvh * 128 + (c & 3) * 32 + quad * 8;
                GLD_LDS16(qkv + kg, &Ks[1 - cur][c * 512]);
            }
        }
        int j0 = t * 64;

        // V register prefetch (consumed after softmax -> latency hidden)
        bf16x8 vf[8][2];
        #pragma unroll
        for (int dt = 0; dt < 8; ++dt) {
            const __bf16* vp = vB + (size_t)(dt * 16 + l16) * S + j0 + quad * 8;
            vf[dt][0] = *(const bf16x8*)(vp);
            vf[dt][1] = *(const bf16x8*)(vp + 32);
        }

        // S = Q @ K^T  (K frags from chunk-swizzled LDS, conflict-free)
        f32x4 s_t[4];
        #pragma unroll
        for (int jt = 0; jt < 4; ++jt) s_t[jt] = zero4;
        #pragma unroll
        for (int jt = 0; jt < 4; ++jt)
            #pragma unroll
            for (int kc = 0; kc < 4; ++kc) {
                bf16x8 kf = *(bf16x8*)&Ks[cur][(jt * 4 + kc) * 512 + lane * 8];
                s_t[jt] = __builtin_amdgcn_mfma_f32_16x16x32_bf16(
                    a_frag[kc], kf, s_t[jt], 0, 0, 0);
            }

        // scale + causal mask (only the last two tiles can touch the diagonal)
        int diag = causal && (t >= nt - 2);
        #pragma unroll
        for (int jt = 0; jt < 4; ++jt)
            #pragma unroll
            for (int r = 0; r < 4; ++r) {
                float sv = s_t[jt][r] * SCALE;
                if (diag && (j0 + jt * 16 + l16 > qrow_d + r)) sv = -1e30f;
                s_t[jt][r] = sv;
            }

        // online softmax: DPP max-reduce, per-lane l partials
        float alpha[4];
        #pragma unroll
        for (int r = 0; r < 4; ++r) {
            float v = fmaxf(fmaxf(s_t[0][r], s_t[1][r]),
                            fmaxf(s_t[2][r], s_t[3][r]));
            v = rowmax16(v);
            float m_new = fmaxf(m_[r], v);
            alpha[r] = __expf(m_[r] - m_new);
            m_[r] = m_new;
            float rs = 0.f;
            #pragma unroll
            for (int jt = 0; jt < 4; ++jt) {
                float p = __expf(s_t[jt][r] - m_new);
                s_t[jt][r] = p;
                rs += p;
            }
            l_[r] = l_[r] * alpha[r] + rs;
        }
        // P (C-layout) -> per-wave LDS region (no barrier needed)
        #pragma unroll
        for (int jt = 0; jt < 4; ++jt)
            #pragma unroll
            for (int r = 0; r < 4; ++r)
                Ps[(wave * 16 + quad * 4 + r) * PS_STR + jt * 16 + l16] =
                    (__bf16)s_t[jt][r];
        #pragma unroll
        for (int dt = 0; dt < 8; ++dt)
            #pragma unroll
            for (int r = 0; r < 4; ++r) o_acc[dt][r] *= alpha[r];

        // P A-frags back from LDS; PV with prefetched V frags
        bf16x8 p0 = *(bf16x8*)&Ps[(wave * 16 + l16) * PS_STR + quad * 8];
        bf16x8 p1 = *(bf16x8*)&Ps[(wave * 16 + l16) * PS_STR + 32 + quad * 8];
        #pragma unroll
        for (int dt = 0; dt < 8; ++dt) {
            o_acc[dt] = __builtin_amdgcn_mfma_f32_16x16x32_bf16(
                p0, vf[dt][0], o_acc[dt], 0, 0, 0);
            o_acc[dt] = __builtin_amdgcn_mfma_f32_16x16x32_bf16(
                p1, vf[dt][1], o_acc[dt], 0, 0, 0);
        }
    }

    // deferred l reduction (DPP) + normalize + store
    float invl[4];
    #pragma unroll
    for (int r = 0; r < 4; ++r) invl[r] = 1.f / rowsum16(l_[r]);
    size_t obase = ((size_t)b * S + q0 + wave * 16 + quad * 4) * 2048
                   + h * 128 + l16;
    #pragma unroll
    for (int dt = 0; dt < 8; ++dt)
        #pragma unroll
        for (int r = 0; r < 4; ++r)
            vo[obase + (size_t)r * 2048 + dt * 16] = (__bf16)(o_acc[dt][r] * invl[r]);
}

// ---------------------------------------------------------------- launch

extern "C" void kernel_launch(void* const* d_in, const int* in_sizes, int n_in,
                              void* d_out, int out_size, void* d_ws, size_t ws_size,
                              hipStream_t stream) {
    const float* x    = (const float*)d_in[0];
    const float* cosp = (const float*)d_in[1];
    const float* sinp = (const float*)d_in[2];
    const float* Wq   = (const float*)d_in[3];
    const float* bq   = (const float*)d_in[4];
    const float* Wkv  = (const float*)d_in[5];
    const float* bkv  = (const float*)d_in[6];
    const float* Wo   = (const float*)d_in[7];
    const float* bo   = (const float*)d_in[8];
    const int* causal = (const int*)d_in[9];
    float* out = (float*)d_out;

    const int B = 2, S = 2048;
    const int M = B * S;  // 4096

    // workspace layout (~60 MB)
    char* w = (char*)d_ws;
    __bf16* x16    = (__bf16*)w; w += (size_t)M * 2048 * 2;     // 16 MB; later = vobuf
    __bf16* Wqkvt  = (__bf16*)w; w += (size_t)3072 * 2048 * 2;  // 12 MB; later = vtg
    __bf16* Wot    = (__bf16*)w; w += (size_t)2048 * 2048 * 2;  //  8 MB
    float*  bqkv   = (float*)w;  w += (size_t)3072 * 4;         // 12 KB
    __bf16* qkvbuf = (__bf16*)w; w += (size_t)M * 3072 * 2;     // 24 MB
    __bf16* vobuf  = x16;    // alias: x16 dead after fused GEMM
    __bf16* vtg    = Wqkvt;  // alias: Wqkvt dead after fused GEMM (4 MB <= 12 MB)

    f32_to_bf16_kernel<<<(M * 2048) / (256 * 8), 256, 0, stream>>>(x, x16, (size_t)M * 2048);
    // fused weight: Wqkvt rows 0..2047 = Wq^T, rows 2048..3071 = Wkv^T
    transpose_to_bf16_kernel<<<dim3(2048 / 32, 2048 / 32), dim3(32, 8), 0, stream>>>(Wq, Wqkvt, 2048, 2048);
    transpose_to_bf16_kernel<<<dim3(1024 / 32, 2048 / 32), dim3(32, 8), 0, stream>>>(Wkv, Wqkvt + (size_t)2048 * 2048, 2048, 1024);
    transpose_to_bf16_kernel<<<dim3(2048 / 32, 2048 / 32), dim3(32, 8), 0, stream>>>(Wo, Wot, 2048, 2048);
    concat_bias_kernel<<<12, 256, 0, stream>>>(bq, bkv, bqkv);
    // fused QKV projection: [4096][3072]
    gemm_bt_bias_kernel<__bf16><<<dim3(M / BM, 3072 / BN), 256, 0, stream>>>(x16, Wqkvt, bqkv, qkvbuf, M, 3072, 2048);
    // RoPE on q (16 head-slots) + k (4 head-slots) in one launch
    {
        int tot = M * 20 * 64;
        rope_kernel<<<(tot + 255) / 256, 256, 0, stream>>>(qkvbuf, cosp, sinp, S, tot);
    }
    // V -> dim-major global layout
    transpose_v_kernel<<<dim3(S / 32, 128 / 32, B * 4), dim3(32, 8), 0, stream>>>(qkvbuf, vtg, S);
    // 512 blocks x 512 threads: id%8 -> (b,kvh); heavy-first causal ordering
    flash_mfma_kernel<<<dim3(512), 512, 0, stream>>>(qkvbuf, vtg, vobuf, causal, S);
    // output projection (fp32 out)
    gemm_bt_bias_kernel<float><<<dim3(M / BM, 2048 / BN), 256, 0, stream>>>(vobuf, Wot, bo, out, M, 2048, 2048);
}

// Round 7
// 443.746 us; speedup vs baseline: 1.1001x; 1.1001x over previous
//
#include <hip/hip_runtime.h>
#include <hip/hip_bf16.h>

typedef __bf16 bf16x8 __attribute__((ext_vector_type(8)));
typedef float  f32x4  __attribute__((ext_vector_type(4)));
typedef unsigned int u32;

// async global->LDS, 16B/lane; LDS dest = wave-uniform base + lane*16 (m97/m104)
#define GLD_LDS16(gp, lp) __builtin_amdgcn_global_load_lds( \
    (const __attribute__((address_space(1))) u32*)(gp), \
    (__attribute__((address_space(3))) u32*)(lp), 16, 0, 0)

// DPP cyclic rotate within 16-lane rows (row_ror:N = 0x120|N) — VALU-pipe cross-lane
template<int CTRL>
__device__ __forceinline__ float dpp_rot(float x) {
    int y = __builtin_amdgcn_update_dpp(__float_as_int(x), __float_as_int(x),
                                        CTRL, 0xF, 0xF, false);
    return __int_as_float(y);
}
__device__ __forceinline__ float rowmax16(float x) {
    x = fmaxf(x, dpp_rot<0x121>(x));
    x = fmaxf(x, dpp_rot<0x122>(x));
    x = fmaxf(x, dpp_rot<0x124>(x));
    x = fmaxf(x, dpp_rot<0x128>(x));
    return x;
}
__device__ __forceinline__ float rowsum16(float x) {
    x += dpp_rot<0x121>(x);
    x += dpp_rot<0x122>(x);
    x += dpp_rot<0x124>(x);
    x += dpp_rot<0x128>(x);
    return x;
}

// ---------------------------------------------------------------- converts

__global__ __launch_bounds__(256) void f32_to_bf16_kernel(
    const float* __restrict__ in, __bf16* __restrict__ out, size_t n) {
    size_t i = ((size_t)blockIdx.x * 256 + threadIdx.x) * 8;
    if (i >= n) return;
    float4 a = *(const float4*)(in + i);
    float4 b = *(const float4*)(in + i + 4);
    bf16x8 v;
    v[0] = (__bf16)a.x; v[1] = (__bf16)a.y; v[2] = (__bf16)a.z; v[3] = (__bf16)a.w;
    v[4] = (__bf16)b.x; v[5] = (__bf16)b.y; v[6] = (__bf16)b.z; v[7] = (__bf16)b.w;
    *(bf16x8*)(out + i) = v;
}

// W[K][N] fp32  ->  Wt[N][K] bf16   (32x32 LDS tile transpose)
__global__ __launch_bounds__(256) void transpose_to_bf16_kernel(
    const float* __restrict__ W, __bf16* __restrict__ Wt, int K, int N) {
    __shared__ float tile[32][33];
    int n0 = blockIdx.x * 32, k0 = blockIdx.y * 32;
    int tx = threadIdx.x, ty = threadIdx.y;  // 32 x 8
    #pragma unroll
    for (int i = 0; i < 32; i += 8)
        tile[ty + i][tx] = W[(size_t)(k0 + ty + i) * N + n0 + tx];
    __syncthreads();
    #pragma unroll
    for (int i = 0; i < 32; i += 8)
        Wt[(size_t)(n0 + ty + i) * K + k0 + tx] = (__bf16)tile[tx][ty + i];
}

// bqkv = concat(bq[2048], bkv[1024])
__global__ __launch_bounds__(256) void concat_bias_kernel(
    const float* __restrict__ bq, const float* __restrict__ bkv,
    float* __restrict__ bqkv) {
    int i = blockIdx.x * 256 + threadIdx.x;
    if (i < 2048) bqkv[i] = bq[i];
    else if (i < 3072) bqkv[i] = bkv[i - 2048];
}

// V cols of qkv [b*S+s][3072] (cols 2560..3071) -> Vt[(b*4+kvh)*128 + d][S]
__global__ __launch_bounds__(256) void transpose_v_kernel(
    const __bf16* __restrict__ qkv, __bf16* __restrict__ vtg, int S) {
    __shared__ __bf16 tile[32][33];
    int s0 = blockIdx.x * 32, d0 = blockIdx.y * 32, z = blockIdx.z;  // z = b*4+kvh
    int b = z >> 2, kvh = z & 3;
    int tx = threadIdx.x, ty = threadIdx.y;  // 32 x 8
    #pragma unroll
    for (int i = 0; i < 32; i += 8)
        tile[ty + i][tx] =
            qkv[((size_t)b * S + s0 + ty + i) * 3072 + 2560 + kvh * 128 + d0 + tx];
    __syncthreads();
    #pragma unroll
    for (int i = 0; i < 32; i += 8)
        vtg[((size_t)z * 128 + d0 + ty + i) * S + s0 + tx] = tile[tx][ty + i];
}

// ---------------------------------------------------------------- GEMM (m97: BK=64)
// C[M][N] = A[M][K](bf16) @ Bt[N][K](bf16)^T + bias[N], fp32 accumulate.
#define BM 128
#define BN 128
#define BK 64

template <typename OutT>
__global__ __launch_bounds__(256) void gemm_bt_bias_kernel(
    const __bf16* __restrict__ A, const __bf16* __restrict__ Bt,
    const float* __restrict__ bias, OutT* __restrict__ C,
    int M, int N, int K) {
    __shared__ __bf16 As[BM * BK];  // 16 KB, 128B rows, unpadded (DMA dest)
    __shared__ __bf16 Bs[BN * BK];
    int tid  = threadIdx.x;
    int bm   = blockIdx.x;
    int bn   = blockIdx.y;
    int wave = tid >> 6;
    int lane = tid & 63;
    int wm   = (wave >> 1) * 64;
    int wn   = (wave & 1) * 64;
    int quad = lane >> 4;
    int l16  = lane & 15;
    int gr   = wave * 32 + (lane >> 3);   // staging row (+i*8)
    int gc   = (lane & 7) * 8;            // staging col (bf16 elems)

    f32x4 acc[4][4];
    f32x4 zero = {0.f, 0.f, 0.f, 0.f};
    #pragma unroll
    for (int i = 0; i < 4; ++i)
        #pragma unroll
        for (int j = 0; j < 4; ++j) acc[i][j] = zero;

    const __bf16* Abase = A  + (size_t)(bm * BM) * K;
    const __bf16* Bbase = Bt + (size_t)(bn * BN) * K;

    for (int k0 = 0; k0 < K; k0 += BK) {
        if (k0) __syncthreads();
        #pragma unroll
        for (int i = 0; i < 4; ++i) {
            GLD_LDS16(Abase + (size_t)(gr + i * 8) * K + k0 + gc,
                      &As[(wave * 32 + i * 8) * BK]);
            GLD_LDS16(Bbase + (size_t)(gr + i * 8) * K + k0 + gc,
                      &Bs[(wave * 32 + i * 8) * BK]);
        }
        __syncthreads();  // drains vmcnt -> LDS data visible

        bf16x8 af[4][2], bf[4][2];
        #pragma unroll
        for (int i = 0; i < 4; ++i)
            #pragma unroll
            for (int kc = 0; kc < 2; ++kc)
                af[i][kc] = *(bf16x8*)&As[(wm + i * 16 + l16) * BK + kc * 32 + quad * 8];
        #pragma unroll
        for (int j = 0; j < 4; ++j)
            #pragma unroll
            for (int kc = 0; kc < 2; ++kc)
                bf[j][kc] = *(bf16x8*)&Bs[(wn + j * 16 + l16) * BK + kc * 32 + quad * 8];
        #pragma unroll
        for (int kc = 0; kc < 2; ++kc)
            #pragma unroll
            for (int i = 0; i < 4; ++i)
                #pragma unroll
                for (int j = 0; j < 4; ++j)
                    acc[i][j] = __builtin_amdgcn_mfma_f32_16x16x32_bf16(
                        af[i][kc], bf[j][kc], acc[i][j], 0, 0, 0);
    }

    // D layout (HW-verified m89/m91): row = quad*4+reg, col = l16
    #pragma unroll
    for (int i = 0; i < 4; ++i) {
        int row = bm * BM + wm + i * 16 + quad * 4;
        #pragma unroll
        for (int j = 0; j < 4; ++j) {
            int col  = bn * BN + wn + j * 16 + l16;
            float bv = bias[col];
            #pragma unroll
            for (int r = 0; r < 4; ++r)
                C[(size_t)(row + r) * N + col] = (OutT)(acc[i][j][r] + bv);
        }
    }
}

// ---------------------------------------------------------------- RoPE (in-place, bf16)
// slots 0..15 = q heads (coloff 0), slots 16..19 = k heads (coloff 2048)
__global__ __launch_bounds__(256) void rope_kernel(
    __bf16* __restrict__ buf, const float* __restrict__ cosp,
    const float* __restrict__ sinp, int S, int total) {
    int idx = blockIdx.x * 256 + threadIdx.x;
    if (idx >= total) return;
    int d    = idx & 63;
    int t2   = idx >> 6;
    int slot = t2 % 20;
    int r    = t2 / 20;
    int s    = r & (S - 1);
    int coloff = (slot < 16) ? slot * 128 : 2048 + (slot - 16) * 128;
    size_t base = (size_t)r * 3072 + coloff;
    float x1 = (float)buf[base + d];
    float x2 = (float)buf[base + d + 64];
    float c  = cosp[s * 64 + d];
    float sn = sinp[s * 64 + d];
    buf[base + d]      = (__bf16)(x1 * c - x2 * sn);
    buf[base + d + 64] = (__bf16)(x1 * sn + x2 * c);
}

// ---------------------------------------------------------------- MFMA flash attention
// Round-5 structure (the 165 µs config): 4 waves/block (256 thr), Q-tile 64
// rows (16/wave), K-tile 64 keys double-buffered in LDS via global_load_lds
// (zero-VGPR prefetch), V register-prefetched from dim-major vtg.
// Round-7 change: UN-paired Q-tiles -> 1024 blocks (3 blocks/CU resident vs
// 2), heavy-first ordering + dispatch-queue slack for causal imbalance.
// C/D layout (m89/m91): row = quad*4+reg, col = l16.
#define PS_STR 68   // 64 keys + 4 pad: P-store banks = 8*quad + l16/2 -> conflict-free

__global__ __launch_bounds__(256, 2) void flash_mfma_kernel(
    const __bf16* __restrict__ qkv,  // [B*S][3072]: q|k(2048..2559)|v
    const __bf16* __restrict__ vtg,  // [(b*4+kvh)*128 + d][S]  (V transposed)
    __bf16* __restrict__ vo,         // [B*S][2048]
    const int* __restrict__ causal_p, int S) {
    __shared__ __bf16 Ks[2][64 * 128];       // 2 x 16 KB, chunk-swizzled
    __shared__ __bf16 Ps[4 * 16 * PS_STR];   // 8.5 KB, per-wave P transform

    const int QKV = 3072;
    int tid  = threadIdx.x;
    int wave = tid >> 6;
    int lane = tid & 63;
    int quad = lane >> 4;
    int l16  = lane & 15;
    int id   = blockIdx.x;
    int xcd  = id & 7;           // id%8 -> (b,kvh): XCD L2 affinity
    int b    = xcd >> 2;
    int kvh  = xcd & 3;
    int rest = id >> 3;          // 0..127
    int hh   = rest & 3;
    int qt   = 31 - (rest >> 2); // heavy (high-qt) blocks dispatch first
    int h    = kvh * 4 + hh;
    int q0   = qt * 64;
    int causal = causal_p[0];
    const float SCALE = 0.08838834764831845f;  // 1/sqrt(128)

    const __bf16* vB = vtg + ((size_t)(b * 4 + kvh) * 128) * S;
    int nt = causal ? (qt + 1) : (S / 64);

    // Q A-frags: lane holds row l16 of the wave's 16-row tile
    bf16x8 a_frag[4];
    {
        size_t qrow = ((size_t)b * S + q0 + wave * 16 + l16) * QKV + h * 128 + quad * 8;
        #pragma unroll
        for (int kc = 0; kc < 4; ++kc)
            a_frag[kc] = *(const bf16x8*)(qkv + qrow + kc * 32);
    }

    f32x4 o_acc[8];
    f32x4 zero4 = {0.f, 0.f, 0.f, 0.f};
    #pragma unroll
    for (int dt = 0; dt < 8; ++dt) o_acc[dt] = zero4;
    float m_[4], l_[4];  // m_: row max; l_: PER-LANE partial sum
    #pragma unroll
    for (int r = 0; r < 4; ++r) { m_[r] = -1e30f; l_[r] = 0.f; }
    int qrow_d = q0 + wave * 16 + quad * 4;

    // prologue: DMA K(0) -> Ks[0]; wave w stages chunks w*4..w*4+3
    {
        size_t kg = ((size_t)b * S + wave * 16 + l16) * QKV + 2048 + kvh * 128 + quad * 8;
        #pragma unroll
        for (int kc = 0; kc < 4; ++kc)
            GLD_LDS16(qkv + kg + kc * 32, &Ks[0][(wave * 4 + kc) * 512]);
    }

    for (int t = 0; t < nt; ++t) {
        int cur = t & 1;
        __syncthreads();  // drains vmcnt: K(t) DMA complete; syncs buffers
        if (t + 1 < nt) {  // prefetch K(t+1) into the other buffer
            size_t kg = ((size_t)b * S + (t + 1) * 64 + wave * 16 + l16) * QKV
                        + 2048 + kvh * 128 + quad * 8;
            #pragma unroll
            for (int kc = 0; kc < 4; ++kc)
                GLD_LDS16(qkv + kg + kc * 32, &Ks[1 - cur][(wave * 4 + kc) * 512]);
        }
        int j0 = t * 64;

        // V register prefetch (consumed after softmax -> latency hidden)
        bf16x8 vf[8][2];
        #pragma unroll
        for (int dt = 0; dt < 8; ++dt) {
            const __bf16* vp = vB + (size_t)(dt * 16 + l16) * S + j0 + quad * 8;
            vf[dt][0] = *(const bf16x8*)(vp);
            vf[dt][1] = *(const bf16x8*)(vp + 32);
        }

        // S = Q @ K^T  (K frags from chunk-swizzled LDS, conflict-free)
        f32x4 s_t[4];
        #pragma unroll
        for (int jt = 0; jt < 4; ++jt) s_t[jt] = zero4;
        #pragma unroll
        for (int jt = 0; jt < 4; ++jt)
            #pragma unroll
            for (int kc = 0; kc < 4; ++kc) {
                bf16x8 kf = *(bf16x8*)&Ks[cur][(jt * 4 + kc) * 512 + lane * 8];
                s_t[jt] = __builtin_amdgcn_mfma_f32_16x16x32_bf16(
                    a_frag[kc], kf, s_t[jt], 0, 0, 0);
            }

        // scale + causal mask (diagonal tile only)
        int diag = causal && (t == nt - 1);
        #pragma unroll
        for (int jt = 0; jt < 4; ++jt)
            #pragma unroll
            for (int r = 0; r < 4; ++r) {
                float sv = s_t[jt][r] * SCALE;
                if (diag && (j0 + jt * 16 + l16 > qrow_d + r)) sv = -1e30f;
                s_t[jt][r] = sv;
            }

        // online softmax: DPP max-reduce, per-lane l partials
        float alpha[4];
        #pragma unroll
        for (int r = 0; r < 4; ++r) {
            float v = fmaxf(fmaxf(s_t[0][r], s_t[1][r]),
                            fmaxf(s_t[2][r], s_t[3][r]));
            v = rowmax16(v);
            float m_new = fmaxf(m_[r], v);
            alpha[r] = __expf(m_[r] - m_new);
            m_[r] = m_new;
            float rs = 0.f;
            #pragma unroll
            for (int jt = 0; jt < 4; ++jt) {
                float p = __expf(s_t[jt][r] - m_new);
                s_t[jt][r] = p;
                rs += p;
            }
            l_[r] = l_[r] * alpha[r] + rs;
        }
        // P (C-layout) -> per-wave LDS region (no barrier needed)
        #pragma unroll
        for (int jt = 0; jt < 4; ++jt)
            #pragma unroll
            for (int r = 0; r < 4; ++r)
                Ps[(wave * 16 + quad * 4 + r) * PS_STR + jt * 16 + l16] =
                    (__bf16)s_t[jt][r];
        #pragma unroll
        for (int dt = 0; dt < 8; ++dt)
            #pragma unroll
            for (int r = 0; r < 4; ++r) o_acc[dt][r] *= alpha[r];

        // P A-frags back from LDS; PV with prefetched V frags
        bf16x8 p0 = *(bf16x8*)&Ps[(wave * 16 + l16) * PS_STR + quad * 8];
        bf16x8 p1 = *(bf16x8*)&Ps[(wave * 16 + l16) * PS_STR + 32 + quad * 8];
        #pragma unroll
        for (int dt = 0; dt < 8; ++dt) {
            o_acc[dt] = __builtin_amdgcn_mfma_f32_16x16x32_bf16(
                p0, vf[dt][0], o_acc[dt], 0, 0, 0);
            o_acc[dt] = __builtin_amdgcn_mfma_f32_16x16x32_bf16(
                p1, vf[dt][1], o_acc[dt], 0, 0, 0);
        }
    }

    // deferred l reduction (DPP) + normalize + store
    float invl[4];
    #pragma unroll
    for (int r = 0; r < 4; ++r) invl[r] = 1.f / rowsum16(l_[r]);
    size_t obase = ((size_t)b * S + q0 + wave * 16 + quad * 4) * 2048
                   + h * 128 + l16;
    #pragma unroll
    for (int dt = 0; dt < 8; ++dt)
        #pragma unroll
        for (int r = 0; r < 4; ++r)
            vo[obase + (size_t)r * 2048 + dt * 16] = (__bf16)(o_acc[dt][r] * invl[r]);
}

// ---------------------------------------------------------------- launch

extern "C" void kernel_launch(void* const* d_in, const int* in_sizes, int n_in,
                              void* d_out, int out_size, void* d_ws, size_t ws_size,
                              hipStream_t stream) {
    const float* x    = (const float*)d_in[0];
    const float* cosp = (const float*)d_in[1];
    const float* sinp = (const float*)d_in[2];
    const float* Wq   = (const float*)d_in[3];
    const float* bq   = (const float*)d_in[4];
    const float* Wkv  = (const float*)d_in[5];
    const float* bkv  = (const float*)d_in[6];
    const float* Wo   = (const float*)d_in[7];
    const float* bo   = (const float*)d_in[8];
    const int* causal = (const int*)d_in[9];
    float* out = (float*)d_out;

    const int B = 2, S = 2048;
    const int M = B * S;  // 4096

    // workspace layout (~60 MB)
    char* w = (char*)d_ws;
    __bf16* x16    = (__bf16*)w; w += (size_t)M * 2048 * 2;     // 16 MB; later = vobuf
    __bf16* Wqkvt  = (__bf16*)w; w += (size_t)3072 * 2048 * 2;  // 12 MB; later = vtg
    __bf16* Wot    = (__bf16*)w; w += (size_t)2048 * 2048 * 2;  //  8 MB
    float*  bqkv   = (float*)w;  w += (size_t)3072 * 4;         // 12 KB
    __bf16* qkvbuf = (__bf16*)w; w += (size_t)M * 3072 * 2;     // 24 MB
    __bf16* vobuf  = x16;    // alias: x16 dead after fused GEMM
    __bf16* vtg    = Wqkvt;  // alias: Wqkvt dead after fused GEMM (4 MB <= 12 MB)

    f32_to_bf16_kernel<<<(M * 2048) / (256 * 8), 256, 0, stream>>>(x, x16, (size_t)M * 2048);
    // fused weight: Wqkvt rows 0..2047 = Wq^T, rows 2048..3071 = Wkv^T
    transpose_to_bf16_kernel<<<dim3(2048 / 32, 2048 / 32), dim3(32, 8), 0, stream>>>(Wq, Wqkvt, 2048, 2048);
    transpose_to_bf16_kernel<<<dim3(1024 / 32, 2048 / 32), dim3(32, 8), 0, stream>>>(Wkv, Wqkvt + (size_t)2048 * 2048, 2048, 1024);
    transpose_to_bf16_kernel<<<dim3(2048 / 32, 2048 / 32), dim3(32, 8), 0, stream>>>(Wo, Wot, 2048, 2048);
    concat_bias_kernel<<<12, 256, 0, stream>>>(bq, bkv, bqkv);
    // fused QKV projection: [4096][3072]
    gemm_bt_bias_kernel<__bf16><<<dim3(M / BM, 3072 / BN), 256, 0, stream>>>(x16, Wqkvt, bqkv, qkvbuf, M, 3072, 2048);
    // RoPE on q (16 head-slots) + k (4 head-slots) in one launch
    {
        int tot = M * 20 * 64;
        rope_kernel<<<(tot + 255) / 256, 256, 0, stream>>>(qkvbuf, cosp, sinp, S, tot);
    }
    // V -> dim-major global layout
    transpose_v_kernel<<<dim3(S / 32, 128 / 32, B * 4), dim3(32, 8), 0, stream>>>(qkvbuf, vtg, S);
    // 1024 blocks x 256 threads: id%8 -> (b,kvh); heavy-first causal ordering
    flash_mfma_kernel<<<dim3(1024), 256, 0, stream>>>(qkvbuf, vtg, vobuf, causal, S);
    // output projection (fp32 out)
    gemm_bt_bias_kernel<float><<<dim3(M / BM, 2048 / BN), 256, 0, stream>>>(vobuf, Wot, bo, out, M, 2048, 2048);
}